// Round 1
// baseline (121.953 us; speedup 1.0000x reference)
//
#include <hip/hip_runtime.h>
#include <hip/hip_bf16.h>

#define NROWS 65536
#define DIM   256
#define KC    512
#define ALPHA 0.05f

#define BM   64
#define BN   64
#define SLD  264   // LDS row stride in bf16 elems (256 + 8 pad -> 528B, 16B-aligned rows)

typedef __attribute__((ext_vector_type(8))) short bf16x8;
typedef __attribute__((ext_vector_type(4))) float f32x4;

static __device__ __forceinline__ unsigned short f2bf(float f) {
    union { __hip_bfloat16 h; unsigned short u; } c;
    c.h = __float2bfloat16(f);
    return c.u;
}
static __device__ __forceinline__ float bf2f(unsigned short u) {
    union { unsigned short u; __hip_bfloat16 h; } c;
    c.u = u;
    return __bfloat162float(c.h);
}

// One wave per center: c_sq (fp32) + bf16-converted centers into workspace.
__global__ void prep_centers(const float* __restrict__ centers,
                             float* __restrict__ c_sq,
                             unsigned short* __restrict__ cbf) {
    const int b = blockIdx.x;      // center index
    const int lane = threadIdx.x;  // 0..63
    const float4 v = reinterpret_cast<const float4*>(centers + (size_t)b * DIM)[lane];
    float s = v.x * v.x + v.y * v.y + v.z * v.z + v.w * v.w;
    ushort4 o;
    o.x = f2bf(v.x); o.y = f2bf(v.y); o.z = f2bf(v.z); o.w = f2bf(v.w);
    reinterpret_cast<ushort4*>(cbf + (size_t)b * DIM)[lane] = o;
    #pragma unroll
    for (int off = 32; off; off >>= 1) s += __shfl_xor(s, off, 64);
    if (lane == 0) c_sq[b] = s;
}

__global__ __launch_bounds__(256, 2) void kmeans_main(
    const float* __restrict__ emb,
    const unsigned short* __restrict__ cbf,
    const float* __restrict__ csq_g,
    float* __restrict__ out) {
    __shared__ unsigned short sA[BM * SLD];   // 33792 B
    __shared__ unsigned short sB[BN * SLD];   // 33792 B
    __shared__ float csq_s[KC];               // 2 KB
    __shared__ float xsq_s[BM];
    __shared__ float rowmin_s[4][BM];         // per-wave row mins

    const int t = threadIdx.x;
    const int w = t >> 6;        // wave 0..3
    const int lane = t & 63;
    const int m = lane & 15;     // MFMA free index
    const int q = lane >> 4;     // 0..3
    const int row0 = blockIdx.x * BM;

    // ---- stage A tile: fp32 global -> bf16 LDS (coalesced float4) ----
    const float4* embv = reinterpret_cast<const float4*>(emb + (size_t)row0 * DIM);
    #pragma unroll
    for (int i = 0; i < 16; ++i) {
        int f = t + 256 * i;      // float4 index within 64x256 tile
        int r = f >> 6;           // 64 float4 per row
        int c4 = f & 63;
        float4 v = embv[r * 64 + c4];
        ushort4 o;
        o.x = f2bf(v.x); o.y = f2bf(v.y); o.z = f2bf(v.z); o.w = f2bf(v.w);
        *reinterpret_cast<ushort4*>(&sA[r * SLD + c4 * 4]) = o;
    }
    csq_s[t] = csq_g[t];
    csq_s[t + 256] = csq_g[t + 256];
    __syncthreads();

    // ---- x_sq per row from staged bf16 (4 lanes per row) ----
    {
        int r = w * 16 + (lane >> 2);
        int qq = lane & 3;
        const ushort4* p = reinterpret_cast<const ushort4*>(&sA[r * SLD + qq * 64]);
        float s = 0.f;
        #pragma unroll
        for (int j = 0; j < 16; ++j) {
            ushort4 u = p[j];
            float a = bf2f(u.x), b = bf2f(u.y), c = bf2f(u.z), d = bf2f(u.w);
            s += a * a + b * b + c * c + d * d;
        }
        s += __shfl_xor(s, 1, 64);
        s += __shfl_xor(s, 2, 64);
        if (qq == 0) xsq_s[r] = s;
    }
    __syncthreads();

    // ---- A fragments register-resident: 4 row-tiles x 8 k-steps ----
    // layout: A[m = lane&15][k = (lane>>4)*8 + j]  (16B contiguous -> ds_read_b128)
    bf16x8 afr[4][8];
    #pragma unroll
    for (int rt = 0; rt < 4; ++rt)
        #pragma unroll
        for (int k = 0; k < 8; ++k)
            afr[rt][k] = *reinterpret_cast<const bf16x8*>(
                &sA[(rt * 16 + m) * SLD + k * 32 + q * 8]);

    float minv[4][4];
    #pragma unroll
    for (int rt = 0; rt < 4; ++rt)
        #pragma unroll
        for (int rg = 0; rg < 4; ++rg) minv[rt][rg] = 1e30f;

    const uint4* cb4 = reinterpret_cast<const uint4*>(cbf);
    for (int ch = 0; ch < 8; ++ch) {
        // stage 64-center bf16 chunk (uint4 = 8 bf16, coalesced)
        #pragma unroll
        for (int i = 0; i < 8; ++i) {
            int f = t + 256 * i;   // uint4 index within 64x256 bf16 tile
            int r = f >> 5;        // 32 uint4 per row
            int c8 = f & 31;
            uint4 v = cb4[(size_t)(ch * BN + r) * 32 + c8];
            *reinterpret_cast<uint4*>(&sB[r * SLD + c8 * 8]) = v;
        }
        __syncthreads();

        // wave w owns col-subtile w of this chunk; B frags reused by 4 row-tiles
        bf16x8 bf[8];
        #pragma unroll
        for (int k = 0; k < 8; ++k)
            bf[k] = *reinterpret_cast<const bf16x8*>(
                &sB[(w * 16 + m) * SLD + k * 32 + q * 8]);

        const int col = ch * 64 + w * 16 + m;
        const float c2 = csq_s[col];
        #pragma unroll
        for (int rt = 0; rt < 4; ++rt) {
            f32x4 acc = {0.f, 0.f, 0.f, 0.f};
            #pragma unroll
            for (int k = 0; k < 8; ++k)
                acc = __builtin_amdgcn_mfma_f32_16x16x32_bf16(afr[rt][k], bf[k], acc, 0, 0, 0);
            // C/D layout: col = lane&15, row = (lane>>4)*4 + reg   [m89/m91]
            #pragma unroll
            for (int rg = 0; rg < 4; ++rg) {
                float x2 = xsq_s[rt * 16 + q * 4 + rg];
                float d2 = x2 + c2 - 2.f * acc[rg];
                minv[rt][rg] = fminf(minv[rt][rg], d2);
            }
        }
        __syncthreads();
    }

    // ---- reduce: min over this wave's 16 cols (xor over lane&15) ----
    #pragma unroll
    for (int rt = 0; rt < 4; ++rt)
        #pragma unroll
        for (int rg = 0; rg < 4; ++rg) {
            float v = minv[rt][rg];
            v = fminf(v, __shfl_xor(v, 1, 64));
            v = fminf(v, __shfl_xor(v, 2, 64));
            v = fminf(v, __shfl_xor(v, 4, 64));
            v = fminf(v, __shfl_xor(v, 8, 64));
            if (m == 0) rowmin_s[w][rt * 16 + q * 4 + rg] = v;
        }
    __syncthreads();

    // ---- combine across the 4 waves' col sets, sqrt, block sum ----
    if (t < 64) {
        float v = fminf(fminf(rowmin_s[0][t], rowmin_s[1][t]),
                        fminf(rowmin_s[2][t], rowmin_s[3][t]));
        float d = sqrtf(fmaxf(v, 0.f));
        #pragma unroll
        for (int off = 1; off < 64; off <<= 1) d += __shfl_xor(d, off, 64);
        if (t == 0) atomicAdd(out, d * (ALPHA / (float)NROWS));
    }
}

extern "C" void kernel_launch(void* const* d_in, const int* in_sizes, int n_in,
                              void* d_out, int out_size, void* d_ws, size_t ws_size,
                              hipStream_t stream) {
    const float* emb     = (const float*)d_in[0];   // [65536, 256] fp32
    const float* centers = (const float*)d_in[1];   // [512, 256] fp32
    float* out = (float*)d_out;                     // scalar fp32

    float* c_sq = (float*)d_ws;                                   // 512 * 4 B
    unsigned short* cbf = (unsigned short*)((char*)d_ws + 2048);  // 512*256 bf16

    hipMemsetAsync(d_out, 0, sizeof(float), stream);
    prep_centers<<<dim3(KC), dim3(64), 0, stream>>>(centers, c_sq, cbf);
    kmeans_main<<<dim3(NROWS / BM), dim3(256), 0, stream>>>(emb, cbf, c_sq, out);
}

// Round 2
// 118.664 us; speedup vs baseline: 1.0277x; 1.0277x over previous
//
#include <hip/hip_runtime.h>
#include <hip/hip_bf16.h>

#define NROWS 65536
#define DIM   256
#define KC    512
#define ALPHA 0.05f

#define BM   64
#define SLD  264   // LDS row stride in bf16 elems (528 B: 16B-aligned, minimal-conflict)

typedef __attribute__((ext_vector_type(8))) short bf16x8;
typedef __attribute__((ext_vector_type(4))) float f32x4;

static __device__ __forceinline__ unsigned short f2bf(float f) {
    union { __hip_bfloat16 h; unsigned short u; } c;
    c.h = __float2bfloat16(f);
    return c.u;
}
static __device__ __forceinline__ float bf2f(unsigned short u) {
    union { unsigned short u; __hip_bfloat16 h; } c;
    c.u = u;
    return __bfloat162float(c.h);
}

// Fragment-major center layout: for chunk ch (64 centers), wave w, k-step kk,
// lane l = q*16+m reads center row ch*64+w*16+m, elems kk*32+q*8 .. +7 (16 B).
// Stored so that uint4 index = ((ch*4+w)*8+kk)*64 + l  -> fully coalesced loads.
__global__ void prep_centers(const float* __restrict__ centers,
                             float* __restrict__ csqh,
                             uint4* __restrict__ cbf2,
                             float* __restrict__ out) {
    const int t = threadIdx.x;
    const int r = blockIdx.x * 8 + (t >> 5);  // center row
    const int e = t & 31;                     // 8-elem group within row
    const float4* cv = reinterpret_cast<const float4*>(centers);
    float4 v0 = cv[r * 64 + e * 2];
    float4 v1 = cv[r * 64 + e * 2 + 1];
    float s = v0.x * v0.x + v0.y * v0.y + v0.z * v0.z + v0.w * v0.w
            + v1.x * v1.x + v1.y * v1.y + v1.z * v1.z + v1.w * v1.w;
    unsigned short o[8];
    o[0] = f2bf(v0.x); o[1] = f2bf(v0.y); o[2] = f2bf(v0.z); o[3] = f2bf(v0.w);
    o[4] = f2bf(v1.x); o[5] = f2bf(v1.y); o[6] = f2bf(v1.z); o[7] = f2bf(v1.w);
    const int ch = r >> 6, w = (r >> 4) & 3, m = r & 15;
    const int kk = e >> 2, q = e & 3, l = q * 16 + m;
    cbf2[(((ch * 4 + w) * 8) + kk) * 64 + l] = *reinterpret_cast<uint4*>(o);
    // sum-of-squares over the 32 threads of this center (stays within 32-group)
    #pragma unroll
    for (int off = 16; off; off >>= 1) s += __shfl_xor(s, off, 64);
    if (e == 0) csqh[r] = 0.5f * s;
    if (blockIdx.x == 0 && t == 0) out[0] = 0.f;  // separate dispatch -> ordered
}

__global__ __launch_bounds__(256, 2) void kmeans_main(
    const float* __restrict__ emb,
    const uint4* __restrict__ cbf2,
    const float* __restrict__ csqh_g,
    float* __restrict__ out) {
    __shared__ unsigned short sA[BM * SLD];   // 33792 B
    __shared__ float xsq_s[BM];
    __shared__ float rowmax_s[4][BM];

    const int t = threadIdx.x;
    const int w = t >> 6;
    const int lane = t & 63;
    const int m = lane & 15;
    const int q = lane >> 4;
    const int row0 = blockIdx.x * BM;

    // ---- stage A tile: fp32 global -> bf16 LDS (coalesced float4) ----
    const float4* embv = reinterpret_cast<const float4*>(emb + (size_t)row0 * DIM);
    #pragma unroll
    for (int i = 0; i < 16; ++i) {
        int f = t + 256 * i;
        int r = f >> 6;
        int c4 = f & 63;
        float4 v = embv[r * 64 + c4];
        ushort4 o;
        o.x = f2bf(v.x); o.y = f2bf(v.y); o.z = f2bf(v.z); o.w = f2bf(v.w);
        *reinterpret_cast<ushort4*>(&sA[r * SLD + c4 * 4]) = o;
    }
    __syncthreads();

    // ---- x_sq per row from staged bf16 (4 lanes per row) ----
    {
        int r = w * 16 + (lane >> 2);
        int qq = lane & 3;
        const ushort4* p = reinterpret_cast<const ushort4*>(&sA[r * SLD + qq * 64]);
        float s = 0.f;
        #pragma unroll
        for (int j = 0; j < 16; ++j) {
            ushort4 u = p[j];
            float a = bf2f(u.x), b = bf2f(u.y), c = bf2f(u.z), d = bf2f(u.w);
            s += a * a + b * b + c * c + d * d;
        }
        s += __shfl_xor(s, 1, 64);
        s += __shfl_xor(s, 2, 64);
        if (qq == 0) xsq_s[r] = s;
    }

    // ---- A fragments register-resident: 4 row-tiles x 8 k-steps ----
    bf16x8 afr[4][8];
    #pragma unroll
    for (int rt = 0; rt < 4; ++rt)
        #pragma unroll
        for (int k = 0; k < 8; ++k)
            afr[rt][k] = *reinterpret_cast<const bf16x8*>(
                &sA[(rt * 16 + m) * SLD + k * 32 + q * 8]);

    // ---- preload c_sq/2 for this wave's 8 column slots ----
    float c2h[8];
    #pragma unroll
    for (int ch = 0; ch < 8; ++ch) c2h[ch] = csqh_g[ch * 64 + w * 16 + m];

    float maxv[4][4];
    #pragma unroll
    for (int rt = 0; rt < 4; ++rt)
        #pragma unroll
        for (int rg = 0; rg < 4; ++rg) maxv[rt][rg] = -1e30f;

    const bf16x8* cb2 = reinterpret_cast<const bf16x8*>(cbf2);

    // ---- barrier-free K-loop: B streamed from L1/L2, 1-chunk prefetch ----
    bf16x8 bcur[8];
    #pragma unroll
    for (int kk = 0; kk < 8; ++kk)
        bcur[kk] = cb2[((0 * 4 + w) * 8 + kk) * 64 + lane];

    #pragma unroll
    for (int ch = 0; ch < 8; ++ch) {
        bf16x8 bnxt[8];
        if (ch < 7) {
            #pragma unroll
            for (int kk = 0; kk < 8; ++kk)
                bnxt[kk] = cb2[(((ch + 1) * 4 + w) * 8 + kk) * 64 + lane];
        }
        const float ci = -c2h[ch];
        f32x4 acc[4];
        #pragma unroll
        for (int rt = 0; rt < 4; ++rt) acc[rt] = (f32x4){ci, ci, ci, ci};
        #pragma unroll
        for (int kk = 0; kk < 8; ++kk)
            #pragma unroll
            for (int rt = 0; rt < 4; ++rt)
                acc[rt] = __builtin_amdgcn_mfma_f32_16x16x32_bf16(
                    afr[rt][kk], bcur[kk], acc[rt], 0, 0, 0);
        #pragma unroll
        for (int rt = 0; rt < 4; ++rt)
            #pragma unroll
            for (int rg = 0; rg < 4; ++rg)
                maxv[rt][rg] = fmaxf(maxv[rt][rg], acc[rt][rg]);
        if (ch < 7) {
            #pragma unroll
            for (int kk = 0; kk < 8; ++kk) bcur[kk] = bnxt[kk];
        }
    }

    // ---- max over this wave's 16 cols (xor over lane&15) ----
    #pragma unroll
    for (int rt = 0; rt < 4; ++rt)
        #pragma unroll
        for (int rg = 0; rg < 4; ++rg) {
            float v = maxv[rt][rg];
            v = fmaxf(v, __shfl_xor(v, 1, 64));
            v = fmaxf(v, __shfl_xor(v, 2, 64));
            v = fmaxf(v, __shfl_xor(v, 4, 64));
            v = fmaxf(v, __shfl_xor(v, 8, 64));
            if (m == 0) rowmax_s[w][rt * 16 + q * 4 + rg] = v;
        }
    __syncthreads();

    // ---- combine waves, d2 = x2 - 2*max(cross - c2/2), sqrt, block sum ----
    if (t < 64) {
        float M = fmaxf(fmaxf(rowmax_s[0][t], rowmax_s[1][t]),
                        fmaxf(rowmax_s[2][t], rowmax_s[3][t]));
        float d = sqrtf(fmaxf(xsq_s[t] - 2.f * M, 0.f));
        #pragma unroll
        for (int off = 1; off < 64; off <<= 1) d += __shfl_xor(d, off, 64);
        if (t == 0) atomicAdd(out, d * (ALPHA / (float)NROWS));
    }
}

extern "C" void kernel_launch(void* const* d_in, const int* in_sizes, int n_in,
                              void* d_out, int out_size, void* d_ws, size_t ws_size,
                              hipStream_t stream) {
    const float* emb     = (const float*)d_in[0];   // [65536, 256] fp32
    const float* centers = (const float*)d_in[1];   // [512, 256] fp32
    float* out = (float*)d_out;

    float* csqh = (float*)d_ws;                       // 512 * 4 B
    uint4* cbf2 = (uint4*)((char*)d_ws + 2048);       // 256 KB fragment-major bf16

    prep_centers<<<dim3(KC / 8), dim3(256), 0, stream>>>(centers, csqh, cbf2, out);
    kmeans_main<<<dim3(NROWS / BM), dim3(256), 0, stream>>>(emb, cbf2, csqh, out);
}